// Round 2
// baseline (647.453 us; speedup 1.0000x reference)
//
#include <hip/hip_runtime.h>

#define N_PTS 786432
#define U_VOX 131072

typedef __attribute__((ext_vector_type(8))) short v8s;
typedef __attribute__((ext_vector_type(4))) float v4f;

__device__ __forceinline__ unsigned short f2bf(float x){
    unsigned u = __float_as_uint(x);
    u += 0x7fffu + ((u >> 16) & 1u);          // RNE
    return (unsigned short)(u >> 16);
}
// monotone f32 <-> u32 encoding for atomic max
__device__ __forceinline__ unsigned encf(float f){
    unsigned u = __float_as_uint(f);
    return (u & 0x80000000u) ? ~u : (u | 0x80000000u);
}
__device__ __forceinline__ float decf(unsigned e){
    unsigned u = (e & 0x80000000u) ? (e & 0x7fffffffu) : ~e;
    return __uint_as_float(u);
}

// ---- fold BN into weights; pack MFMA B-fragment layouts (bf16) --------------
__global__ __launch_bounds__(256) void k_fold(
    const float* __restrict__ bn0, const float* __restrict__ w1,
    const float* __restrict__ b1,  const float* __restrict__ bn2,
    const float* __restrict__ w2,  const float* __restrict__ b2,
    const float* __restrict__ bn5, const float* __restrict__ w3,
    const float* __restrict__ b3,  const float* __restrict__ bn8,
    const float* __restrict__ w4,
    float* __restrict__ w1ff, float* __restrict__ b1ff,
    float* __restrict__ b2f,  float* __restrict__ b3f,
    unsigned short* __restrict__ wp2, unsigned short* __restrict__ wp3,
    unsigned short* __restrict__ wp4)
{
    __shared__ float s0[9],t0[9],s2[64],t2[64],s5[128],t5[128],s8[256],t8[256];
    int tid = threadIdx.x;
    if (tid < 9){  float g=bn0[tid], b=bn0[9+tid],  m=bn0[18+tid],  v=bn0[27+tid];
        float s=g*rsqrtf(v+1e-5f); s0[tid]=s; t0[tid]=b-m*s; }
    if (tid < 64){ float g=bn2[tid], b=bn2[64+tid], m=bn2[128+tid], v=bn2[192+tid];
        float s=g*rsqrtf(v+1e-5f); s2[tid]=s; t2[tid]=b-m*s; }
    if (tid < 128){float g=bn5[tid], b=bn5[128+tid],m=bn5[256+tid], v=bn5[384+tid];
        float s=g*rsqrtf(v+1e-5f); s5[tid]=s; t5[tid]=b-m*s; }
    { float g=bn8[tid], b=bn8[256+tid], m=bn8[512+tid], v=bn8[768+tid];
        float s=g*rsqrtf(v+1e-5f); s8[tid]=s; t8[tid]=b-m*s; }
    __syncthreads();
    if (blockIdx.x == 0){
        for (int i=tid;i<576;i+=256){ int k=i>>6, j=i&63; w1ff[i]=s0[k]*w1[i]*s2[j]; }
        if (tid < 64){ float a=0.f;
            for (int k=0;k<9;k++) a += t0[k]*w1[k*64+tid];
            b1ff[tid]=(a+b1[tid])*s2[tid]+t2[tid]; }
        if (tid<128) b2f[tid]=b2[tid]*s5[tid]+t5[tid];
        b3f[tid]=b3[tid]*s8[tid]+t8[tid];
    }
    const int g0 = blockIdx.x*256 + tid, gstep = 32*256;
    for (int e=g0;e<8192;e+=gstep){          // W2f: 64x128, NT=8
        int i=e&7, l=(e>>3)&63, jt=(e>>9)&7, ks=(e>>12)&1;
        int k=ks*32+((l>>4)<<3)+i, j=jt*16+(l&15);
        wp2[e]=f2bf(w2[k*128+j]*s5[j]);
    }
    for (int e=g0;e<32768;e+=gstep){         // W3f: 128x256, NT=16
        int i=e&7, l=(e>>3)&63, jt=(e>>9)&15, ks=e>>13;
        int k=ks*32+((l>>4)<<3)+i, j=jt*16+(l&15);
        wp3[e]=f2bf(w3[k*256+j]*s8[j]);
    }
    for (int e=g0;e<65536;e+=gstep){         // W4: 256x256, NT=16
        int i=e&7, l=(e>>3)&63, jt=(e>>9)&15, ks=e>>13;
        int k=ks*32+((l>>4)<<3)+i, j=jt*16+(l&15);
        wp4[e]=f2bf(w4[k*256+j]);
    }
}

// ---- fused per-point MLP (9->64->128->256->256) + encoded atomic segment-max -
__global__ __launch_bounds__(256) void k_fused(
    const float* __restrict__ cat, const float* __restrict__ occ,
    const int* __restrict__ uinv,
    const float* __restrict__ w1ff, const float* __restrict__ b1ff,
    const unsigned short* __restrict__ wp2, const float* __restrict__ b2f,
    const unsigned short* __restrict__ wp3, const float* __restrict__ b3f,
    const unsigned short* __restrict__ wp4, const float* __restrict__ b4,
    unsigned* __restrict__ pooled)
{
    __shared__ __align__(16) char smem[39424];
    float* bw   = (float*)smem;                            // w1(576)+b1(64)+b2(128)+b3(256)+b4(256)
    float* socc = (float*)(smem+5120);
    int*   svox = (int*)  (smem+5376);
    float* scat = (float*)(smem+5632);                     // 64x12 f32
    unsigned short* sh1 = (unsigned short*)(smem+8704);    // 64x72 bf16
    unsigned short* sh2 = (unsigned short*)(smem+17920);   // 64x136 bf16
    unsigned short* sh3 = (unsigned short*)(smem+5632);    // 64x264 bf16 (overlaps scat/sh1/sh2 — phased)

    const int tid = threadIdx.x;
    const int p0  = blockIdx.x*64;

    for (int i=tid;i<576;i+=256) bw[i]=w1ff[i];
    if (tid<64)  bw[576+tid]=b1ff[tid];
    if (tid<128) bw[640+tid]=b2f[tid];
    bw[768+tid]=b3f[tid];
    bw[1024+tid]=b4[tid];
    for (int i=tid;i<576;i+=256){ int p=i/9, k=i-p*9; scat[p*12+k]=cat[(size_t)p0*9+i]; }
    if (tid<64){ socc[tid]=occ[p0+tid]; svox[tid]=uinv[p0+tid]; }
    __syncthreads();

    // ---- layer 1 (VALU): 4 threads/point, 16 cols each ----
    {
        const int p=tid>>2, jq=(tid&3)*16;
        float h[16];
#pragma unroll
        for (int jj=0;jj<16;jj++) h[jj]=bw[576+jq+jj];
#pragma unroll
        for (int k=0;k<9;k++){
            float fv=scat[p*12+k];
#pragma unroll
            for (int jj=0;jj<16;jj++) h[jj] += fv*bw[k*64+jq+jj];
        }
        unsigned pk[8];
#pragma unroll
        for (int q=0;q<8;q++){
            unsigned lo=f2bf(fmaxf(h[2*q],0.f));
            unsigned hi=f2bf(fmaxf(h[2*q+1],0.f));
            pk[q]=lo|(hi<<16);
        }
        uint4* dst=(uint4*)(sh1 + p*72 + jq);
        dst[0]=make_uint4(pk[0],pk[1],pk[2],pk[3]);
        dst[1]=make_uint4(pk[4],pk[5],pk[6],pk[7]);
    }
    __syncthreads();

    const int w=tid>>6, l=tid&63;
    const int lrow=l&15, lkb=(l>>4)<<3;
    v4f acc[4][4];

    // ---- layer 2 (MFMA): [64x64]@[64x128]; wave w owns cols [w*32, w*32+32) ----
#pragma unroll
    for (int mt=0;mt<4;mt++)
#pragma unroll
    for (int jt=0;jt<2;jt++)
#pragma unroll
    for (int r=0;r<4;r++) acc[mt][jt][r]=0.f;
    const unsigned short* wp2w = wp2 + (size_t)w*1024 + (size_t)l*8;
#pragma unroll
    for (int ks=0;ks<2;ks++){
        v8s a[4], b[2];
#pragma unroll
        for (int mt=0;mt<4;mt++)
            a[mt]=*(const v8s*)(sh1 + (mt*16+lrow)*72 + ks*32 + lkb);
#pragma unroll
        for (int jt=0;jt<2;jt++)
            b[jt]=*(const v8s*)(wp2w + ks*4096 + jt*512);
#pragma unroll
        for (int mt=0;mt<4;mt++)
#pragma unroll
        for (int jt=0;jt<2;jt++)
            acc[mt][jt]=__builtin_amdgcn_mfma_f32_16x16x32_bf16(a[mt],b[jt],acc[mt][jt],0,0,0);
    }
#pragma unroll
    for (int mt=0;mt<4;mt++)
#pragma unroll
    for (int jt=0;jt<2;jt++)
#pragma unroll
    for (int r=0;r<4;r++){
        int prow=mt*16+(l>>4)*4+r;
        int j=w*32+jt*16+lrow;
        sh2[prow*136+j]=f2bf(fmaxf(acc[mt][jt][r]+bw[640+j],0.f));
    }
    __syncthreads();

    // ---- layer 3 (MFMA): [64x128]@[128x256]; wave w owns cols [w*64, w*64+64) ----
#pragma unroll
    for (int mt=0;mt<4;mt++)
#pragma unroll
    for (int jt=0;jt<4;jt++)
#pragma unroll
    for (int r=0;r<4;r++) acc[mt][jt][r]=0.f;
    const unsigned short* wp3w = wp3 + (size_t)w*2048 + (size_t)l*8;
#pragma unroll
    for (int ks=0;ks<4;ks++){
        v8s a[4], b[4];
#pragma unroll
        for (int mt=0;mt<4;mt++)
            a[mt]=*(const v8s*)(sh2 + (mt*16+lrow)*136 + ks*32 + lkb);
#pragma unroll
        for (int jt=0;jt<4;jt++)
            b[jt]=*(const v8s*)(wp3w + ks*8192 + jt*512);
#pragma unroll
        for (int mt=0;mt<4;mt++)
#pragma unroll
        for (int jt=0;jt<4;jt++)
            acc[mt][jt]=__builtin_amdgcn_mfma_f32_16x16x32_bf16(a[mt],b[jt],acc[mt][jt],0,0,0);
    }
    __syncthreads();   // all sh2 reads done before sh3 (overlapping) is written
#pragma unroll
    for (int mt=0;mt<4;mt++)
#pragma unroll
    for (int jt=0;jt<4;jt++)
#pragma unroll
    for (int r=0;r<4;r++){
        int prow=mt*16+(l>>4)*4+r;
        int j=w*64+jt*16+lrow;
        sh3[prow*264+j]=f2bf(fmaxf(acc[mt][jt][r]+bw[768+j],0.f));
    }
    __syncthreads();

    // ---- layer 4 (MFMA): [64x256]@[256x256] + masked encoded atomic max ----
#pragma unroll
    for (int mt=0;mt<4;mt++)
#pragma unroll
    for (int jt=0;jt<4;jt++)
#pragma unroll
    for (int r=0;r<4;r++) acc[mt][jt][r]=0.f;
    const unsigned short* wp4w = wp4 + (size_t)w*2048 + (size_t)l*8;
#pragma unroll
    for (int ks=0;ks<8;ks++){
        v8s a[4], b[4];
#pragma unroll
        for (int mt=0;mt<4;mt++)
            a[mt]=*(const v8s*)(sh3 + (mt*16+lrow)*264 + ks*32 + lkb);
#pragma unroll
        for (int jt=0;jt<4;jt++)
            b[jt]=*(const v8s*)(wp4w + ks*8192 + jt*512);
#pragma unroll
        for (int mt=0;mt<4;mt++)
#pragma unroll
        for (int jt=0;jt<4;jt++)
            acc[mt][jt]=__builtin_amdgcn_mfma_f32_16x16x32_bf16(a[mt],b[jt],acc[mt][jt],0,0,0);
    }
#pragma unroll
    for (int mt=0;mt<4;mt++)
#pragma unroll
    for (int jt=0;jt<4;jt++)
#pragma unroll
    for (int r=0;r<4;r++){
        int prow=mt*16+(l>>4)*4+r;
        int j=w*64+jt*16+lrow;
        float v=(acc[mt][jt][r]+bw[1024+j])*socc[prow];
        atomicMax(pooled + (size_t)svox[prow]*256 + j, encf(v));
    }
}

// ---- max point-index per voxel ----------------------------------------------
__global__ void k_idx(const int* __restrict__ uinv, int* __restrict__ uidx){
    int i=blockIdx.x*256+threadIdx.x;
    atomicMax(uidx + uinv[i], i);
}

// ---- head: relu(pooled@wc+bc)*pooled_occupy; writes outputs 1 and 2 ---------
__global__ __launch_bounds__(256) void k_head(const unsigned* __restrict__ pooled,
        const float* __restrict__ wc, const float* __restrict__ bc,
        const float* __restrict__ occ, const int* __restrict__ uidx,
        float* __restrict__ outf)
{
    __shared__ float swc[4096];
    int tid=threadIdx.x;
    for (int i=tid;i<4096;i+=256) swc[i]=wc[i];
    __syncthreads();
    int j=tid&15, vg=tid>>4;
    int vox=blockIdx.x*16+vg;
    const unsigned* pe=pooled+(size_t)vox*256;
    float acc=bc[j];
    for (int k0=0;k0<256;k0+=4){
        uint4 e=*(const uint4*)(pe+k0);
        acc += decf(e.x)*swc[(k0+0)*16+j];
        acc += decf(e.y)*swc[(k0+1)*16+j];
        acc += decf(e.z)*swc[(k0+2)*16+j];
        acc += decf(e.w)*swc[(k0+3)*16+j];
    }
    float pocc=occ[uidx[vox]];
    outf[524288 + (size_t)vox*16 + j] = fmaxf(acc,0.f)*pocc;
    if (j==0) outf[2621440 + vox] = pocc;
}

// ---- unq pass-through (runs LAST: overwrites the temp region in d_out) ------
__global__ void k_unq(const int* __restrict__ unq, float* __restrict__ o){
    int i=blockIdx.x*256+threadIdx.x;
    o[i]=(float)unq[i];
}

extern "C" void kernel_launch(void* const* d_in, const int* in_sizes, int n_in,
                              void* d_out, int out_size, void* d_ws, size_t ws_size,
                              hipStream_t stream)
{
    const float* cat =(const float*)d_in[0];
    const float* occ =(const float*)d_in[1];
    const int*   unq =(const int*)  d_in[2];
    const int*   uinv=(const int*)  d_in[3];
    const float* bn0 =(const float*)d_in[4];
    const float* w1  =(const float*)d_in[5];
    const float* b1  =(const float*)d_in[6];
    const float* bn2 =(const float*)d_in[7];
    const float* w2  =(const float*)d_in[8];
    const float* b2  =(const float*)d_in[9];
    const float* bn5 =(const float*)d_in[10];
    const float* w3  =(const float*)d_in[11];
    const float* b3  =(const float*)d_in[12];
    const float* bn8 =(const float*)d_in[13];
    const float* w4  =(const float*)d_in[14];
    const float* b4  =(const float*)d_in[15];
    const float* wc  =(const float*)d_in[16];
    const float* bc  =(const float*)d_in[17];

    // ws: ONLY the 128 MiB pooled buffer
    unsigned* pooled = (unsigned*)d_ws;

    // temporaries live in d_out's unq region [0, 524288) floats; k_unq runs last
    float* outf = (float*)d_out;
    int*   uidx = (int*)d_out;                         // [0 .. 131072) as int
    float* w1ff = outf + 131072;                       // 576
    float* b1ff = w1ff + 576;                          // 64
    float* b2f  = b1ff + 64;                           // 128
    float* b3f  = b2f  + 128;                          // 256  (ends at 132096)
    unsigned short* wp2 = (unsigned short*)(outf + 132096);   // 8192 u16
    unsigned short* wp3 = wp2 + 8192;                          // 32768 u16
    unsigned short* wp4 = wp3 + 32768;                         // 65536 u16 (ends float idx 185344 < 524288)

    hipMemsetAsync((void*)pooled, 0, (size_t)U_VOX*256*4, stream);  // enc(-inf)=0
    hipMemsetAsync((void*)uidx,   0, (size_t)U_VOX*4, stream);      // idx >= 0
    k_fold  <<<32,        256,0,stream>>>(bn0,w1,b1,bn2,w2,b2,bn5,w3,b3,bn8,w4,
                                          w1ff,b1ff,b2f,b3f,wp2,wp3,wp4);
    k_idx   <<<N_PTS/256, 256,0,stream>>>(uinv,uidx);
    k_fused <<<N_PTS/64,  256,0,stream>>>(cat,occ,uinv,w1ff,b1ff,wp2,b2f,wp3,b3f,
                                          wp4,b4,pooled);
    k_head  <<<U_VOX/16,  256,0,stream>>>(pooled,wc,bc,occ,uidx,outf);
    k_unq   <<<U_VOX*4/256,256,0,stream>>>(unq,outf);
}